// Round 10
// baseline (34.273 us; speedup 1.0000x reference)
//
#include <hip/hip_runtime.h>
#include <math.h>

#define SEQ 30
#define H 64
#define VOCAB 128000

#define NB 1000
#define ITERS 8               // rows per block = 16 * ITERS = 128
#define ROWS_PER_BLOCK 128

// ws layout: floats [0,64) = h_new; byte 512: (NB+1) x u64 slots
//   slots[0..NB)  packed (M,S) per block   slots[NB] = packed lse (low word flag)
#define WS_H 0
#define SLOT_BYTE_OFF 512
#define SENTINEL (~0ULL)

#define AGENT __HIP_MEMORY_SCOPE_AGENT

// ---- K1: sentinel re-arm + in-wave GRU (64 lanes, no barriers) ----
__global__ void gru_kernel(const float* __restrict__ input,
                           const float* __restrict__ hidden,
                           const float* __restrict__ W_ih,
                           const float* __restrict__ W_hh,
                           const float* __restrict__ b_ih,
                           const float* __restrict__ b_hh,
                           float* __restrict__ out,
                           float* __restrict__ ws,
                           unsigned long long* __restrict__ slots) {
    const int j = threadIdx.x;  // 64 lanes
    // re-arm all NB+1 sentinel slots for this replay
    for (int i = j; i < NB + 1; i += 64) slots[i] = SENTINEL;

    float s0 = 0.f;  // softmax over singleton axis => attn weights all 1.0
#pragma unroll
    for (int i = 0; i < SEQ; ++i) s0 += input[i * H + j];
    const float h0 = hidden[j];

    // lane j owns gate rows j (r), 64+j (z), 128+j (n)
    float a0 = b_ih[j], a1 = b_ih[H + j], a2 = b_ih[2 * H + j];
    float c0 = b_hh[j], c1 = b_hh[H + j], c2 = b_hh[2 * H + j];
    const float4* Wi4 = (const float4*)W_ih;
    const float4* Wh4 = (const float4*)W_hh;
#pragma unroll
    for (int k = 0; k < H / 4; ++k) {
        const float x0 = __shfl(s0, 4 * k + 0), x1 = __shfl(s0, 4 * k + 1);
        const float x2 = __shfl(s0, 4 * k + 2), x3 = __shfl(s0, 4 * k + 3);
        const float g0 = __shfl(h0, 4 * k + 0), g1 = __shfl(h0, 4 * k + 1);
        const float g2 = __shfl(h0, 4 * k + 2), g3 = __shfl(h0, 4 * k + 3);
        float4 u;
        u = Wi4[j * 16 + k];           a0 += u.x*x0 + u.y*x1 + u.z*x2 + u.w*x3;
        u = Wi4[(H + j) * 16 + k];     a1 += u.x*x0 + u.y*x1 + u.z*x2 + u.w*x3;
        u = Wi4[(2 * H + j) * 16 + k]; a2 += u.x*x0 + u.y*x1 + u.z*x2 + u.w*x3;
        u = Wh4[j * 16 + k];           c0 += u.x*g0 + u.y*g1 + u.z*g2 + u.w*g3;
        u = Wh4[(H + j) * 16 + k];     c1 += u.x*g0 + u.y*g1 + u.z*g2 + u.w*g3;
        u = Wh4[(2 * H + j) * 16 + k]; c2 += u.x*g0 + u.y*g1 + u.z*g2 + u.w*g3;
    }
    const float r = 1.f / (1.f + expf(-(a0 + c0)));
    const float z = 1.f / (1.f + expf(-(a1 + c1)));
    const float n = tanhf(a2 + r * c2);
    const float hn = (1.f - z) * n + z * h0;
    ws[WS_H + j] = hn;
    out[VOCAB + j] = hn;   // second tuple output: h_new
}

// ---- K2: GEMV (inline) + slot publish; merger block reduces; others poll lse
__global__ void __launch_bounds__(256, 4) logits_finish_kernel(
        const float* __restrict__ W_out,
        const float* __restrict__ b_out,
        float* __restrict__ out,
        const float* __restrict__ ws,
        unsigned long long* __restrict__ slots) {
    __shared__ __align__(16) float hs[H];
    __shared__ float slog[ROWS_PER_BLOCK];
    __shared__ float pm[16], ps[16];
    __shared__ float rm[256], rs[256];
    __shared__ float s_lse;

    const int t = threadIdx.x;
    const int sub = t & 15;
    const int grp = t >> 4;
    const int bid = blockIdx.x;
    const int base = bid * ROWS_PER_BLOCK;
    const float4* __restrict__ W4 = (const float4*)W_out;

    if (t < H) hs[t] = ws[WS_H + t];   // kernel boundary made h_new visible
    __syncthreads();
    const float4 hv = ((const float4*)hs)[sub];

    // ---- GEMV: load inline, consume immediately (R8-validated: no spill) ----
    float logit[ITERS];
#pragma unroll
    for (int it = 0; it < ITERS; ++it) {
        const int row = base + it * 16 + grp;
        // flat float4 index = base*16 + it*256 + t -> fully sequential per block
        const float4 w = W4[row * 16 + sub];
        float d = w.x * hv.x + w.y * hv.y + w.z * hv.z + w.w * hv.w;
#pragma unroll
        for (int off = 1; off < 16; off <<= 1) d += __shfl_xor(d, off);
        if (sub == 0) {
            const float lg = d + b_out[row];
            logit[it] = lg;
            slog[it * 16 + grp] = lg;  // parked in LDS across the wait
        }
    }
    if (sub == 0) {
        float m = logit[0];
#pragma unroll
        for (int it = 1; it < ITERS; ++it) m = fmaxf(m, logit[it]);
        float s = 0.f;
#pragma unroll
        for (int it = 0; it < ITERS; ++it) s += expf(logit[it] - m);
        pm[grp] = m;
        ps[grp] = s;
    }
    __syncthreads();

    // ---- publish own partial: ONE relaxed 8B store, own cacheline ----
    if (t == 0) {
        float M = pm[0], S = 0.f;
#pragma unroll
        for (int i = 1; i < 16; ++i) M = fmaxf(M, pm[i]);
#pragma unroll
        for (int i = 0; i < 16; ++i) S += ps[i] * expf(pm[i] - M);
        const unsigned long long pk =
            ((unsigned long long)__float_as_uint(S) << 32) |
            (unsigned long long)__float_as_uint(M);
        __hip_atomic_store(&slots[bid], pk, __ATOMIC_RELAXED, AGENT);
    }

    float lse;
    if (bid == NB - 1) {
        // ---- merger block: only these 256 threads poll the slots ----
        float m = -INFINITY, s = 0.f;
        for (int i = t; i < NB; i += 256) {
            unsigned long long v;
            while ((v = __hip_atomic_load(&slots[i], __ATOMIC_RELAXED, AGENT)) ==
                   SENTINEL)
                __builtin_amdgcn_s_sleep(1);
            const float m2 = __uint_as_float((unsigned)(v & 0xFFFFFFFFu));
            const float s2 = __uint_as_float((unsigned)(v >> 32));
            const float Mn = fmaxf(m, m2);
            s = s * expf(m - Mn) + s2 * expf(m2 - Mn);
            m = Mn;
        }
        rm[t] = m; rs[t] = s;
        __syncthreads();
        for (int off = 128; off > 0; off >>= 1) {
            if (t < off) {
                const float m2 = rm[t + off], s2 = rs[t + off];
                const float Mn = fmaxf(rm[t], m2);
                rs[t] = rs[t] * expf(rm[t] - Mn) + s2 * expf(m2 - Mn);
                rm[t] = Mn;
            }
            __syncthreads();
        }
        lse = rm[0] + logf(rs[0]);
        if (t == 0) {
            // publish: low word flag (1 != 0xFFFFFFFF), high word lse bits
            const unsigned long long pk =
                ((unsigned long long)__float_as_uint(lse) << 32) | 1ull;
            __hip_atomic_store(&slots[NB], pk, __ATOMIC_RELAXED, AGENT);
        }
    } else {
        // ---- followers: only t0 polls one read-only line; rest are parked ----
        if (t == 0) {
            unsigned long long v;
            while ((v = __hip_atomic_load(&slots[NB], __ATOMIC_RELAXED, AGENT)) ==
                   SENTINEL)
                __builtin_amdgcn_s_sleep(2);
            s_lse = __uint_as_float((unsigned)(v >> 32));
        }
        __syncthreads();
        lse = s_lse;
    }

    // ---- final store: 128 contiguous floats per block ----
    if (t < ROWS_PER_BLOCK) out[base + t] = slog[t] - lse;
}

extern "C" void kernel_launch(void* const* d_in, const int* in_sizes, int n_in,
                              void* d_out, int out_size, void* d_ws, size_t ws_size,
                              hipStream_t stream) {
    const float* input  = (const float*)d_in[0];
    const float* hidden = (const float*)d_in[1];
    // d_in[2] = W_attn, d_in[3] = b_attn: dead (softmax over singleton axis)
    const float* W_ih   = (const float*)d_in[4];
    const float* W_hh   = (const float*)d_in[5];
    const float* b_ih   = (const float*)d_in[6];
    const float* b_hh   = (const float*)d_in[7];
    const float* W_out  = (const float*)d_in[8];
    const float* b_out  = (const float*)d_in[9];
    // d_in[10] = time_step: unused
    float* out = (float*)d_out;
    float* ws  = (float*)d_ws;
    unsigned long long* slots =
        (unsigned long long*)((char*)d_ws + SLOT_BYTE_OFF);

    gru_kernel<<<1, 64, 0, stream>>>(input, hidden, W_ih, W_hh, b_ih, b_hh,
                                     out, ws, slots);
    logits_finish_kernel<<<NB, 256, 0, stream>>>(W_out, b_out, out, ws, slots);
}

// Round 12
// 33.066 us; speedup vs baseline: 1.0365x; 1.0365x over previous
//
#include <hip/hip_runtime.h>
#include <math.h>

#define SEQ 30
#define H 64
#define VOCAB 128000

#define NB 1000
#define ITERS 8               // rows per block = 16 * ITERS = 128
#define ROWS_PER_BLOCK 128

// ws layout (floats): [0..NB) per-block max, [1024..1024+NB) sum, [2048..2112) h_new
#define WS_M 0
#define WS_S 1024
#define WS_H 2048

// ---- K1: in-wave GRU (64 lanes, no barriers; R10-validated) ----
__global__ void gru_kernel(const float* __restrict__ input,
                           const float* __restrict__ hidden,
                           const float* __restrict__ W_ih,
                           const float* __restrict__ W_hh,
                           const float* __restrict__ b_ih,
                           const float* __restrict__ b_hh,
                           float* __restrict__ out,
                           float* __restrict__ ws) {
    const int j = threadIdx.x;  // 64 lanes

    float s0 = 0.f;  // softmax over singleton axis => attn weights all 1.0
#pragma unroll
    for (int i = 0; i < SEQ; ++i) s0 += input[i * H + j];
    const float h0 = hidden[j];

    // lane j owns gate rows j (r), 64+j (z), 128+j (n)
    float a0 = b_ih[j], a1 = b_ih[H + j], a2 = b_ih[2 * H + j];
    float c0 = b_hh[j], c1 = b_hh[H + j], c2 = b_hh[2 * H + j];
    const float4* Wi4 = (const float4*)W_ih;
    const float4* Wh4 = (const float4*)W_hh;
#pragma unroll
    for (int k = 0; k < H / 4; ++k) {
        const float x0 = __shfl(s0, 4 * k + 0), x1 = __shfl(s0, 4 * k + 1);
        const float x2 = __shfl(s0, 4 * k + 2), x3 = __shfl(s0, 4 * k + 3);
        const float g0 = __shfl(h0, 4 * k + 0), g1 = __shfl(h0, 4 * k + 1);
        const float g2 = __shfl(h0, 4 * k + 2), g3 = __shfl(h0, 4 * k + 3);
        float4 u;
        u = Wi4[j * 16 + k];           a0 += u.x*x0 + u.y*x1 + u.z*x2 + u.w*x3;
        u = Wi4[(H + j) * 16 + k];     a1 += u.x*x0 + u.y*x1 + u.z*x2 + u.w*x3;
        u = Wi4[(2 * H + j) * 16 + k]; a2 += u.x*x0 + u.y*x1 + u.z*x2 + u.w*x3;
        u = Wh4[j * 16 + k];           c0 += u.x*g0 + u.y*g1 + u.z*g2 + u.w*g3;
        u = Wh4[(H + j) * 16 + k];     c1 += u.x*g0 + u.y*g1 + u.z*g2 + u.w*g3;
        u = Wh4[(2 * H + j) * 16 + k]; c2 += u.x*g0 + u.y*g1 + u.z*g2 + u.w*g3;
    }
    const float r = 1.f / (1.f + expf(-(a0 + c0)));
    const float z = 1.f / (1.f + expf(-(a1 + c1)));
    const float n = tanhf(a2 + r * c2);
    const float hn = (1.f - z) * n + z * h0;
    ws[WS_H + j] = hn;
    out[VOCAB + j] = hn;   // second tuple output: h_new
}

// ---- K2: GEMV with 8-deep load prefetch (ILP), LSE partials, coalesced store
__global__ void __launch_bounds__(256, 4) logits_kernel(
        const float* __restrict__ W_out,
        const float* __restrict__ b_out,
        float* __restrict__ out,
        float* __restrict__ ws) {
    __shared__ __align__(16) float hs[H];
    __shared__ float slog[ROWS_PER_BLOCK];
    __shared__ float pm[16], ps[16];
    const int t = threadIdx.x;
    const int sub = t & 15;
    const int grp = t >> 4;
    const int base = blockIdx.x * ROWS_PER_BLOCK;
    const float4* __restrict__ W4 = (const float4*)W_out;

    // 1) issue ALL global loads first: 8 float4 W rows/lane + 8 b_out (8-deep MLP)
    float4 w[ITERS];
    float bo[ITERS];
#pragma unroll
    for (int it = 0; it < ITERS; ++it) {
        const int row = base + it * 16 + grp;
        // flat float4 index = base*16 + it*256 + t -> fully sequential per block
        w[it] = W4[row * 16 + sub];
        bo[it] = b_out[row];
    }

    // 2) h fragment via LDS (barrier also drains this block's own loads)
    if (t < H) hs[t] = ws[WS_H + t];
    __syncthreads();
    const float4 hv = ((const float4*)hs)[sub];

    // 3) dots + per-block LSE partial (all operands in registers)
    float logit[ITERS];
#pragma unroll
    for (int it = 0; it < ITERS; ++it) {
        float d = w[it].x * hv.x + w[it].y * hv.y + w[it].z * hv.z + w[it].w * hv.w;
#pragma unroll
        for (int off = 1; off < 16; off <<= 1) d += __shfl_xor(d, off);
        logit[it] = d + bo[it];
        if (sub == 0) slog[it * 16 + grp] = logit[it];
    }
    if (sub == 0) {
        float m = logit[0];
#pragma unroll
        for (int it = 1; it < ITERS; ++it) m = fmaxf(m, logit[it]);
        float s = 0.f;
#pragma unroll
        for (int it = 0; it < ITERS; ++it) s += expf(logit[it] - m);
        pm[grp] = m;
        ps[grp] = s;
    }
    __syncthreads();
    // coalesced logit store: 128 contiguous floats
    if (t < ROWS_PER_BLOCK) out[base + t] = slog[t];
    if (t == 0) {
        float M = pm[0], S = 0.f;
#pragma unroll
        for (int i = 1; i < 16; ++i) M = fmaxf(M, pm[i]);
#pragma unroll
        for (int i = 0; i < 16; ++i) S += ps[i] * expf(pm[i] - M);
        ws[WS_M + blockIdx.x] = M;
        ws[WS_S + blockIdx.x] = S;
    }
}

// ---- K3: redundant LSE merge (8 KB from L2 per block) + in-place subtract ----
__global__ void __launch_bounds__(256) finish_kernel(float* __restrict__ out,
                                                     const float* __restrict__ ws) {
    __shared__ float pm[256], ps[256];
    const int t = threadIdx.x;
    float m = -INFINITY, s = 0.f;
    for (int i = t; i < NB; i += 256) {
        const float m2 = ws[WS_M + i], s2 = ws[WS_S + i];
        const float Mn = fmaxf(m, m2);
        s = s * expf(m - Mn) + s2 * expf(m2 - Mn);
        m = Mn;
    }
    pm[t] = m; ps[t] = s;
    __syncthreads();
    for (int off = 128; off > 0; off >>= 1) {
        if (t < off) {
            const float m2 = pm[t + off], s2 = ps[t + off];
            const float Mn = fmaxf(pm[t], m2);
            ps[t] = ps[t] * expf(pm[t] - Mn) + s2 * expf(m2 - Mn);
            pm[t] = Mn;
        }
        __syncthreads();
    }
    const float lse = pm[0] + logf(ps[0]);

    // exactly one float4 per thread: 125 blocks * 256 threads = 32000 float4
    const int i = blockIdx.x * 256 + t;
    float4* o4 = (float4*)out;
    float4 v = o4[i];
    v.x -= lse; v.y -= lse; v.z -= lse; v.w -= lse;
    o4[i] = v;
}

extern "C" void kernel_launch(void* const* d_in, const int* in_sizes, int n_in,
                              void* d_out, int out_size, void* d_ws, size_t ws_size,
                              hipStream_t stream) {
    const float* input  = (const float*)d_in[0];
    const float* hidden = (const float*)d_in[1];
    // d_in[2] = W_attn, d_in[3] = b_attn: dead (softmax over singleton axis)
    const float* W_ih   = (const float*)d_in[4];
    const float* W_hh   = (const float*)d_in[5];
    const float* b_ih   = (const float*)d_in[6];
    const float* b_hh   = (const float*)d_in[7];
    const float* W_out  = (const float*)d_in[8];
    const float* b_out  = (const float*)d_in[9];
    // d_in[10] = time_step: unused
    float* out = (float*)d_out;
    float* ws  = (float*)d_ws;

    gru_kernel<<<1, 64, 0, stream>>>(input, hidden, W_ih, W_hh, b_ih, b_hh, out, ws);
    logits_kernel<<<NB, 256, 0, stream>>>(W_out, b_out, out, ws);
    finish_kernel<<<VOCAB / 4 / 256, 256, 0, stream>>>(out, ws);
}

// Round 13
// 21.493 us; speedup vs baseline: 1.5946x; 1.5384x over previous
//
#include <hip/hip_runtime.h>
#include <math.h>

#define SEQ 30
#define H 64
#define VOCAB 128000

#define NB 1000
#define ITERS 8               // rows per block = 16 * ITERS = 128
#define ROWS_PER_BLOCK (16 * ITERS)

// ws layout (floats): [0..NB) per-block max, [1024..1024+NB) sum, [2048..2112) h_new
#define WS_M 0
#define WS_S 1024
#define WS_H 2048

// ---- K1: GRU, 768 threads / 12 waves, coalesced prefetched W loads ----
// thread t = (row r = t>>2, quarter q = t&3): 16 cols of W_ih[r] and W_hh[r]
__global__ void gru_kernel(const float* __restrict__ input,
                           const float* __restrict__ hidden,
                           const float* __restrict__ W_ih,
                           const float* __restrict__ W_hh,
                           const float* __restrict__ b_ih,
                           const float* __restrict__ b_hh,
                           float* __restrict__ out,
                           float* __restrict__ ws) {
    __shared__ __align__(16) float xs[H], h0s[H];
    __shared__ float gx[3 * H], gh[3 * H];
    const int t = threadIdx.x;   // 768
    const int r = t >> 2;        // 0..191  (gate row)
    const int q = t & 3;         // 0..3    (column quarter)

    // 1) issue all W loads first: 8 independent float4 per thread, one round trip
    const float4* Wi4 = (const float4*)W_ih;
    const float4* Wh4 = (const float4*)W_hh;
    float4 wi[4], wh[4];
#pragma unroll
    for (int k = 0; k < 4; ++k) {
        wi[k] = Wi4[r * 16 + q * 4 + k];
        wh[k] = Wh4[r * 16 + q * 4 + k];
    }

    // 2) wave 0 computes attention sum + h0 while the W stream is in flight
    if (t < H) {
        float s = 0.f;  // softmax over singleton axis => attn weights all 1.0
#pragma unroll
        for (int i = 0; i < SEQ; ++i) s += input[i * H + t];
        xs[t] = s;
        h0s[t] = hidden[t];
    }
    __syncthreads();

    // 3) partial dots (operands all in registers/LDS), 4-lane reduce
    const float4* xs4 = (const float4*)xs;
    const float4* h04 = (const float4*)h0s;
    float pi = 0.f, ph = 0.f;
#pragma unroll
    for (int k = 0; k < 4; ++k) {
        const float4 xv = xs4[q * 4 + k], hv = h04[q * 4 + k];
        pi += wi[k].x * xv.x + wi[k].y * xv.y + wi[k].z * xv.z + wi[k].w * xv.w;
        ph += wh[k].x * hv.x + wh[k].y * hv.y + wh[k].z * hv.z + wh[k].w * hv.w;
    }
    pi += __shfl_xor(pi, 1); pi += __shfl_xor(pi, 2);
    ph += __shfl_xor(ph, 1); ph += __shfl_xor(ph, 2);
    if (q == 0) {
        gx[r] = pi + b_ih[r];
        gh[r] = ph + b_hh[r];
    }
    __syncthreads();

    // 4) gate math on 64 threads
    if (t < H) {
        const float rr = 1.f / (1.f + expf(-(gx[t] + gh[t])));
        const float zz = 1.f / (1.f + expf(-(gx[H + t] + gh[H + t])));
        const float nn = tanhf(gx[2 * H + t] + rr * gh[2 * H + t]);
        const float hn = (1.f - zz) * nn + zz * h0s[t];
        ws[WS_H + t] = hn;
        out[VOCAB + t] = hn;   // second tuple output: h_new
    }
}

// ---- K2: logits = h_new @ W_out^T + b_out (inline loads, R5-exact) ----
__global__ void __launch_bounds__(256, 4) logits_kernel(
        const float* __restrict__ W_out,
        const float* __restrict__ b_out,
        float* __restrict__ out,
        float* __restrict__ ws) {
    __shared__ float hs[H];
    __shared__ float slog[ROWS_PER_BLOCK];
    __shared__ float pm[16], ps[16];
    const int t = threadIdx.x;
    const int sub = t & 15;
    const int grp = t >> 4;
    const int base = blockIdx.x * ROWS_PER_BLOCK;
    const float4* __restrict__ W4 = (const float4*)W_out;

    if (t < H) hs[t] = ws[WS_H + t];
    __syncthreads();
    const float4 hv = ((const float4*)hs)[sub];

    float logit[ITERS];
#pragma unroll
    for (int it = 0; it < ITERS; ++it) {
        const int row = base + it * 16 + grp;
        // flat float4 index = base*16 + it*256 + t -> fully sequential per block
        const float4 w = W4[row * 16 + sub];
        float d = w.x * hv.x + w.y * hv.y + w.z * hv.z + w.w * hv.w;
#pragma unroll
        for (int off = 1; off < 16; off <<= 1) d += __shfl_xor(d, off);
        logit[it] = d + b_out[row];
        if (sub == 0) slog[it * 16 + grp] = logit[it];
    }
    if (sub == 0) {
        float m = logit[0];
#pragma unroll
        for (int it = 1; it < ITERS; ++it) m = fmaxf(m, logit[it]);
        float s = 0.f;
#pragma unroll
        for (int it = 0; it < ITERS; ++it) s += expf(logit[it] - m);
        pm[grp] = m;
        ps[grp] = s;
    }
    __syncthreads();
    // coalesced logit store: 128 contiguous floats
    if (t < ROWS_PER_BLOCK) out[base + t] = slog[t];
    if (t == 0) {
        float M = pm[0], S = 0.f;
#pragma unroll
        for (int i = 1; i < 16; ++i) M = fmaxf(M, pm[i]);
#pragma unroll
        for (int i = 0; i < 16; ++i) S += ps[i] * expf(pm[i] - M);
        ws[WS_M + blockIdx.x] = M;
        ws[WS_S + blockIdx.x] = S;
    }
}

// ---- K3: redundant LSE merge (8 KB from L2 per block) + in-place subtract ----
__global__ void __launch_bounds__(256) finish_kernel(float* __restrict__ out,
                                                     const float* __restrict__ ws) {
    __shared__ float pm[256], ps[256];
    const int t = threadIdx.x;
    float m = -INFINITY, s = 0.f;
    for (int i = t; i < NB; i += 256) {
        const float m2 = ws[WS_M + i], s2 = ws[WS_S + i];
        const float Mn = fmaxf(m, m2);
        s = s * expf(m - Mn) + s2 * expf(m2 - Mn);
        m = Mn;
    }
    pm[t] = m; ps[t] = s;
    __syncthreads();
    for (int off = 128; off > 0; off >>= 1) {
        if (t < off) {
            const float m2 = pm[t + off], s2 = ps[t + off];
            const float Mn = fmaxf(pm[t], m2);
            ps[t] = ps[t] * expf(pm[t] - Mn) + s2 * expf(m2 - Mn);
            pm[t] = Mn;
        }
        __syncthreads();
    }
    const float lse = pm[0] + logf(ps[0]);

    // exactly one float4 per thread: 125 blocks * 256 threads = 32000 float4
    const int i = blockIdx.x * 256 + t;
    float4* o4 = (float4*)out;
    float4 v = o4[i];
    v.x -= lse; v.y -= lse; v.z -= lse; v.w -= lse;
    o4[i] = v;
}

extern "C" void kernel_launch(void* const* d_in, const int* in_sizes, int n_in,
                              void* d_out, int out_size, void* d_ws, size_t ws_size,
                              hipStream_t stream) {
    const float* input  = (const float*)d_in[0];
    const float* hidden = (const float*)d_in[1];
    // d_in[2] = W_attn, d_in[3] = b_attn: dead (softmax over singleton axis)
    const float* W_ih   = (const float*)d_in[4];
    const float* W_hh   = (const float*)d_in[5];
    const float* b_ih   = (const float*)d_in[6];
    const float* b_hh   = (const float*)d_in[7];
    const float* W_out  = (const float*)d_in[8];
    const float* b_out  = (const float*)d_in[9];
    // d_in[10] = time_step: unused
    float* out = (float*)d_out;
    float* ws  = (float*)d_ws;

    gru_kernel<<<1, 768, 0, stream>>>(input, hidden, W_ih, W_hh, b_ih, b_hh, out, ws);
    logits_kernel<<<NB, 256, 0, stream>>>(W_out, b_out, out, ws);
    finish_kernel<<<VOCAB / 4 / 256, 256, 0, stream>>>(out, ws);
}

// Round 14
// 20.419 us; speedup vs baseline: 1.6785x; 1.0526x over previous
//
#include <hip/hip_runtime.h>
#include <math.h>

#define SEQ 30
#define H 64
#define VOCAB 128000

#define NB 1000
#define ITERS 8               // rows per block = 16 * ITERS = 128
#define ROWS_PER_BLOCK (16 * ITERS)

// ws layout (floats): [0..NB) per-block max, [1024..1024+NB) sum, [2048..2112) h_new
#define WS_M 0
#define WS_S 1024
#define WS_H 2048

// ---- K1: GRU, 768 threads / 12 waves, coalesced prefetched W loads ----
// thread t = (row r = t>>2, quarter q = t&3): 16 cols of W_ih[r] and W_hh[r]
__global__ void gru_kernel(const float* __restrict__ input,
                           const float* __restrict__ hidden,
                           const float* __restrict__ W_ih,
                           const float* __restrict__ W_hh,
                           const float* __restrict__ b_ih,
                           const float* __restrict__ b_hh,
                           float* __restrict__ out,
                           float* __restrict__ ws) {
    __shared__ __align__(16) float xs[H], h0s[H];
    __shared__ float gx[3 * H], gh[3 * H];
    const int t = threadIdx.x;   // 768
    const int r = t >> 2;        // 0..191  (gate row)
    const int q = t & 3;         // 0..3    (column quarter)

    // 1) issue all W loads first: 8 independent float4 per thread, one round trip
    const float4* Wi4 = (const float4*)W_ih;
    const float4* Wh4 = (const float4*)W_hh;
    float4 wi[4], wh[4];
#pragma unroll
    for (int k = 0; k < 4; ++k) {
        wi[k] = Wi4[r * 16 + q * 4 + k];
        wh[k] = Wh4[r * 16 + q * 4 + k];
    }

    // 2) wave 0 computes attention sum + h0 while the W stream is in flight
    if (t < H) {
        float s = 0.f;  // softmax over singleton axis => attn weights all 1.0
#pragma unroll
        for (int i = 0; i < SEQ; ++i) s += input[i * H + t];
        xs[t] = s;
        h0s[t] = hidden[t];
    }
    __syncthreads();

    // 3) partial dots (operands all in registers/LDS), 4-lane reduce
    const float4* xs4 = (const float4*)xs;
    const float4* h04 = (const float4*)h0s;
    float pi = 0.f, ph = 0.f;
#pragma unroll
    for (int k = 0; k < 4; ++k) {
        const float4 xv = xs4[q * 4 + k], hv = h04[q * 4 + k];
        pi += wi[k].x * xv.x + wi[k].y * xv.y + wi[k].z * xv.z + wi[k].w * xv.w;
        ph += wh[k].x * hv.x + wh[k].y * hv.y + wh[k].z * hv.z + wh[k].w * hv.w;
    }
    pi += __shfl_xor(pi, 1); pi += __shfl_xor(pi, 2);
    ph += __shfl_xor(ph, 1); ph += __shfl_xor(ph, 2);
    if (q == 0) {
        gx[r] = pi + b_ih[r];
        gh[r] = ph + b_hh[r];
    }
    __syncthreads();

    // 4) gate math on 64 threads
    if (t < H) {
        const float rr = 1.f / (1.f + expf(-(gx[t] + gh[t])));
        const float zz = 1.f / (1.f + expf(-(gx[H + t] + gh[H + t])));
        const float nn = tanhf(gx[2 * H + t] + rr * gh[2 * H + t]);
        const float hn = (1.f - zz) * nn + zz * h0s[t];
        ws[WS_H + t] = hn;
        out[VOCAB + t] = hn;   // second tuple output: h_new
    }
}

// ---- K2: GEMV, 8-deep load prefetch (ILP), LSE partials, coalesced store ----
__global__ void __launch_bounds__(256, 4) logits_kernel(
        const float* __restrict__ W_out,
        const float* __restrict__ b_out,
        float* __restrict__ out,
        float* __restrict__ ws) {
    __shared__ __align__(16) float hs[H];
    __shared__ float slog[ROWS_PER_BLOCK];
    __shared__ float pm[16], ps[16];
    const int t = threadIdx.x;
    const int sub = t & 15;
    const int grp = t >> 4;
    const int base = blockIdx.x * ROWS_PER_BLOCK;
    const float4* __restrict__ W4 = (const float4*)W_out;

    // 1) issue ALL global loads first: one deep round-trip window per wave
    float4 w[ITERS];
    float bo[ITERS];
#pragma unroll
    for (int it = 0; it < ITERS; ++it) {
        const int row = base + it * 16 + grp;
        // flat float4 index = base*16 + it*256 + t -> fully sequential per block
        w[it] = W4[row * 16 + sub];
        bo[it] = b_out[row];
    }

    // 2) h fragment via LDS (barrier also drains this block's own loads)
    if (t < H) hs[t] = ws[WS_H + t];
    __syncthreads();
    const float4 hv = ((const float4*)hs)[sub];

    // 3) dots + per-block LSE partial (all operands in registers)
    float logit[ITERS];
#pragma unroll
    for (int it = 0; it < ITERS; ++it) {
        float d = w[it].x * hv.x + w[it].y * hv.y + w[it].z * hv.z + w[it].w * hv.w;
#pragma unroll
        for (int off = 1; off < 16; off <<= 1) d += __shfl_xor(d, off);
        logit[it] = d + bo[it];
        if (sub == 0) slog[it * 16 + grp] = logit[it];
    }
    if (sub == 0) {
        float m = logit[0];
#pragma unroll
        for (int it = 1; it < ITERS; ++it) m = fmaxf(m, logit[it]);
        float s = 0.f;
#pragma unroll
        for (int it = 0; it < ITERS; ++it) s += expf(logit[it] - m);
        pm[grp] = m;
        ps[grp] = s;
    }
    __syncthreads();
    // coalesced logit store: 128 contiguous floats
    if (t < ROWS_PER_BLOCK) out[base + t] = slog[t];
    if (t == 0) {
        float M = pm[0], S = 0.f;
#pragma unroll
        for (int i = 1; i < 16; ++i) M = fmaxf(M, pm[i]);
#pragma unroll
        for (int i = 0; i < 16; ++i) S += ps[i] * expf(pm[i] - M);
        ws[WS_M + blockIdx.x] = M;
        ws[WS_S + blockIdx.x] = S;
    }
}

// ---- K3: redundant LSE merge (8 KB from L2 per block) + in-place subtract ----
__global__ void __launch_bounds__(256) finish_kernel(float* __restrict__ out,
                                                     const float* __restrict__ ws) {
    __shared__ float pm[256], ps[256];
    const int t = threadIdx.x;
    float m = -INFINITY, s = 0.f;
    for (int i = t; i < NB; i += 256) {
        const float m2 = ws[WS_M + i], s2 = ws[WS_S + i];
        const float Mn = fmaxf(m, m2);
        s = s * expf(m - Mn) + s2 * expf(m2 - Mn);
        m = Mn;
    }
    pm[t] = m; ps[t] = s;
    __syncthreads();
    for (int off = 128; off > 0; off >>= 1) {
        if (t < off) {
            const float m2 = pm[t + off], s2 = ps[t + off];
            const float Mn = fmaxf(pm[t], m2);
            ps[t] = ps[t] * expf(pm[t] - Mn) + s2 * expf(m2 - Mn);
            pm[t] = Mn;
        }
        __syncthreads();
    }
    const float lse = pm[0] + logf(ps[0]);

    // exactly one float4 per thread: 125 blocks * 256 threads = 32000 float4
    const int i = blockIdx.x * 256 + t;
    float4* o4 = (float4*)out;
    float4 v = o4[i];
    v.x -= lse; v.y -= lse; v.z -= lse; v.w -= lse;
    o4[i] = v;
}

extern "C" void kernel_launch(void* const* d_in, const int* in_sizes, int n_in,
                              void* d_out, int out_size, void* d_ws, size_t ws_size,
                              hipStream_t stream) {
    const float* input  = (const float*)d_in[0];
    const float* hidden = (const float*)d_in[1];
    // d_in[2] = W_attn, d_in[3] = b_attn: dead (softmax over singleton axis)
    const float* W_ih   = (const float*)d_in[4];
    const float* W_hh   = (const float*)d_in[5];
    const float* b_ih   = (const float*)d_in[6];
    const float* b_hh   = (const float*)d_in[7];
    const float* W_out  = (const float*)d_in[8];
    const float* b_out  = (const float*)d_in[9];
    // d_in[10] = time_step: unused
    float* out = (float*)d_out;
    float* ws  = (float*)d_ws;

    gru_kernel<<<1, 768, 0, stream>>>(input, hidden, W_ih, W_hh, b_ih, b_hh, out, ws);
    logits_kernel<<<NB, 256, 0, stream>>>(W_out, b_out, out, ws);
    finish_kernel<<<VOCAB / 4 / 256, 256, 0, stream>>>(out, ws);
}